// Round 13
// baseline (1504.838 us; speedup 1.0000x reference)
//
#include <hip/hip_runtime.h>
#include <hip/hip_fp16.h>

typedef _Float16 f16;
typedef _Float16 half4 __attribute__((ext_vector_type(4)));
typedef _Float16 half8 __attribute__((ext_vector_type(8)));
typedef float floatx4 __attribute__((ext_vector_type(4)));

constexpr int kH  = 2048;
constexpr int kS  = 2048;
constexpr int kB  = 2;
constexpr int kT  = kB * kS;   // 4096 tokens
constexpr int kNH = 16;
constexpr int kHD = 128;
constexpr int kE  = 8;
constexpr int kF  = 8192;
constexpr int kCAP = 1280;     // ceil(T*K/E*1.25)
constexpr int kTK = kT * 2;

__device__ __forceinline__ void gload16(const void* g, void* lds_) {
  __builtin_amdgcn_global_load_lds((const __attribute__((address_space(1))) void*)g,
                                   (__attribute__((address_space(3))) void*)lds_,
                                   16, 0, 0);
}

// XCD-chunked bijective remap (requires nwg % 8 == 0). Use ONLY for qkvg and
// attn (operands fit L2). NOT for MoE GEMMs (r5: L3 thrash; r8: SWAPXY also
// hurts -- default N-fastest order is best there). r11: 128^2 occupancy-2
// tile also worse (2x B-traffic + half the MFMA per phase) -- 256^2 stays.
__device__ __forceinline__ void xcd_remap(int& bx, int& by, int& bz) {
  const int gx = gridDim.x, gy = gridDim.y;
  const int nwg = gx * gy * gridDim.z;
  int L = (bz * gy + by) * gx + bx;
  L = (L & 7) * (nwg >> 3) + (L >> 3);
  bz = L / (gx * gy);
  const int r = L - bz * gx * gy;
  by = r / gx;  bx = r - by * gx;
}

// ---------------- transpose + fp32->fp16 convert: src[K][N] -> dst[N][K] ----
__global__ __launch_bounds__(256) void transpose_cvt(
    const float* __restrict__ src, f16* __restrict__ dst,
    int ldS, int ldD, long sZ, long dZ)
{
  __shared__ float tile[64][65];
  src += (long)blockIdx.z * sZ;
  dst += (long)blockIdx.z * dZ;
  const int kb = blockIdx.y * 64, nb = blockIdx.x * 64;
  const int tx = threadIdx.x & 15, ty = threadIdx.x >> 4;
#pragma unroll
  for (int i = 0; i < 4; i++) {
    const int r = ty + i * 16;
    const float4 v = *(const float4*)&src[(long)(kb + r) * ldS + nb + tx * 4];
    tile[r][tx * 4 + 0] = v.x; tile[r][tx * 4 + 1] = v.y;
    tile[r][tx * 4 + 2] = v.z; tile[r][tx * 4 + 3] = v.w;
  }
  __syncthreads();
  const int tx8 = threadIdx.x & 7, ty32 = threadIdx.x >> 3;
#pragma unroll
  for (int i = 0; i < 2; i++) {
    const int n = ty32 + i * 32;
    union { f16 h[8]; float4 v; } pk;
#pragma unroll
    for (int j = 0; j < 8; j++) pk.h[j] = (f16)tile[tx8 * 8 + j][n];
    *(float4*)&dst[(long)(nb + n) * ldD + kb + tx8 * 8] = pk.v;
  }
}

// ---- batched 2048x2048 transpose-convert of the 5 attention weights --------
__global__ __launch_bounds__(256) void transpose_cvt5(
    const float* __restrict__ s0, const float* __restrict__ s1,
    const float* __restrict__ s2, const float* __restrict__ s3,
    const float* __restrict__ s4, f16* __restrict__ dst)
{
  __shared__ float tile[64][65];
  const float* src;
  switch (blockIdx.z) {
    case 0: src = s0; break;
    case 1: src = s1; break;
    case 2: src = s2; break;
    case 3: src = s3; break;
    default: src = s4; break;
  }
  dst += (long)blockIdx.z * kH * kH;
  const int kb = blockIdx.y * 64, nb = blockIdx.x * 64;
  const int tx = threadIdx.x & 15, ty = threadIdx.x >> 4;
#pragma unroll
  for (int i = 0; i < 4; i++) {
    const int r = ty + i * 16;
    const float4 v = *(const float4*)&src[(long)(kb + r) * kH + nb + tx * 4];
    tile[r][tx * 4 + 0] = v.x; tile[r][tx * 4 + 1] = v.y;
    tile[r][tx * 4 + 2] = v.z; tile[r][tx * 4 + 3] = v.w;
  }
  __syncthreads();
  const int tx8 = threadIdx.x & 7, ty32 = threadIdx.x >> 3;
#pragma unroll
  for (int i = 0; i < 2; i++) {
    const int n = ty32 + i * 32;
    union { f16 h[8]; float4 v; } pk;
#pragma unroll
    for (int j = 0; j < 8; j++) pk.h[j] = (f16)tile[tx8 * 8 + j][n];
    *(float4*)&dst[(long)(nb + n) * kH + kb + tx8 * 8] = pk.v;
  }
}

// ---------------- f16 -> f16 transpose (V relayout) -------------------------
__global__ __launch_bounds__(256) void transpose_f16(
    const f16* __restrict__ src, f16* __restrict__ dst,
    int ldS, int ldD, long sZ, long dZ)
{
  __shared__ f16 tile[64][80];
  src += (long)blockIdx.z * sZ;
  dst += (long)blockIdx.z * dZ;
  const int kb = blockIdx.y * 64, nb = blockIdx.x * 64;
  const int tx = threadIdx.x & 7, ty = threadIdx.x >> 3;  // 8 x 32
#pragma unroll
  for (int i = 0; i < 2; i++) {
    const int r = ty + i * 32;
    *(half8*)&tile[r][tx * 8] =
        *(const half8*)&src[(long)(kb + r) * ldS + nb + tx * 8];
  }
  __syncthreads();
#pragma unroll
  for (int i = 0; i < 2; i++) {
    const int n = ty + i * 32;
    union { f16 h[8]; float4 v; } pk;
#pragma unroll
    for (int j = 0; j < 8; j++) pk.h[j] = tile[tx * 8 + j][n];
    *(float4*)&dst[(long)(nb + n) * ldD + kb + tx * 8] = pk.v;
  }
}

// ---------------- layernorm: one block (256 thr) per row of 2048 ------------
__global__ __launch_bounds__(256) void ln_kernel(
    const float* __restrict__ x, const float* __restrict__ sc,
    const float* __restrict__ bi, f16* __restrict__ o16, float* __restrict__ o32)
{
  const long row = blockIdx.x;
  const float* xr = x + row * kH;
  const int t = threadIdx.x;
  const float4 u = ((const float4*)xr)[t * 2];
  const float4 v = ((const float4*)xr)[t * 2 + 1];
  float s = u.x + u.y + u.z + u.w + v.x + v.y + v.z + v.w;
  float q = u.x*u.x + u.y*u.y + u.z*u.z + u.w*u.w + v.x*v.x + v.y*v.y + v.z*v.z + v.w*v.w;
#pragma unroll
  for (int m = 1; m < 64; m <<= 1) { s += __shfl_xor(s, m); q += __shfl_xor(q, m); }
  __shared__ float red_s[4], red_q[4];
  const int w = t >> 6, l = t & 63;
  if (l == 0) { red_s[w] = s; red_q[w] = q; }
  __syncthreads();
  s = red_s[0] + red_s[1] + red_s[2] + red_s[3];
  q = red_q[0] + red_q[1] + red_q[2] + red_q[3];
  const float mean = s * (1.f / kH);
  const float var = q * (1.f / kH) - mean * mean;
  const float rstd = rsqrtf(var + 1e-5f);
  const int c = t * 8;
  const float vals[8] = {u.x, u.y, u.z, u.w, v.x, v.y, v.z, v.w};
#pragma unroll
  for (int j = 0; j < 8; j++) {
    const float y = (vals[j] - mean) * rstd * sc[c + j] + bi[c + j];
    o16[row * kH + c + j] = (f16)y;
    if (o32 != nullptr) o32[row * kH + c + j] = y;
  }
}

// ---------------- 256x256 8-phase pipelined GEMM ----------------------------
// C[M][N] = A[M][K] * B^T[N][K], f16 in / f32 acc. 8 waves (2Mx4N), per-wave
// C = 128x64. K-tile = 64 (2 kc-halves of 32). LDS = 8 units of 16KB.
// Per-phase vmcnt(10) retires the unit staged 6 phases (~1200cy) ago.
// SK-way split-K: z = expert*SK + kq; partials written cZ2 apart.
#define STG(SRC, TILE, KC, PAR, MAT) { \
  const f16* s_ = (SRC) + (long)(TILE) * 64 + (KC) * 32; \
  char* d_ = lds + ((PAR) * 65536 + (MAT) * 32768 + (KC) * 16384) + ldsW; \
  gload16(s_, d_); \
  gload16(s_ + 128 * ldGl, d_ + 8192); }

#define MROW(MH, MM, AF) \
  acc[(MH)*4+(MM)][0] = __builtin_amdgcn_mfma_f32_16x16x32_f16(AF, bf0, acc[(MH)*4+(MM)][0], 0, 0, 0); \
  acc[(MH)*4+(MM)][1] = __builtin_amdgcn_mfma_f32_16x16x32_f16(AF, bf1, acc[(MH)*4+(MM)][1], 0, 0, 0); \
  acc[(MH)*4+(MM)][2] = __builtin_amdgcn_mfma_f32_16x16x32_f16(AF, bf2, acc[(MH)*4+(MM)][2], 0, 0, 0); \
  acc[(MH)*4+(MM)][3] = __builtin_amdgcn_mfma_f32_16x16x32_f16(AF, bf3, acc[(MH)*4+(MM)][3], 0, 0, 0);

#define PH(PAR, KC, MH, RB, STAGE_STMT, VM_STMT) { \
  const char* au_ = lds + ((PAR) * 65536 + (KC) * 16384); \
  const char* bu_ = lds + ((PAR) * 65536 + 32768 + (KC) * 16384); \
  af0 = *(const half8*)(au_ + afoff + (MH) * 4096 +    0); \
  af1 = *(const half8*)(au_ + afoff + (MH) * 4096 + 1024); \
  af2 = *(const half8*)(au_ + afoff + (MH) * 4096 + 2048); \
  af3 = *(const half8*)(au_ + afoff + (MH) * 4096 + 3072); \
  if (RB) { \
    bf0 = *(const half8*)(bu_ + bfoff +    0); \
    bf1 = *(const half8*)(bu_ + bfoff + 1024); \
    bf2 = *(const half8*)(bu_ + bfoff + 2048); \
    bf3 = *(const half8*)(bu_ + bfoff + 3072); \
  } \
  STAGE_STMT; \
  VM_STMT; \
  __builtin_amdgcn_sched_barrier(0); \
  __builtin_amdgcn_s_barrier(); \
  asm volatile("s_waitcnt lgkmcnt(0)" ::: "memory"); \
  __builtin_amdgcn_sched_barrier(0); \
  __builtin_amdgcn_s_setprio(1); \
  MROW(MH, 0, af0) MROW(MH, 1, af1) MROW(MH, 2, af2) MROW(MH, 3, af3) \
  __builtin_amdgcn_s_setprio(0); }

#define VM10 asm volatile("s_waitcnt vmcnt(10)" ::: "memory")
#define VM8  asm volatile("s_waitcnt vmcnt(8)" ::: "memory")
#define VM4  asm volatile("s_waitcnt vmcnt(4)" ::: "memory")
#define VM0  asm volatile("s_waitcnt vmcnt(0)" ::: "memory")
#define NOP (void)0

// EPI: 0 f32 store; 2 f16 gelu(x+bias); 3 f16 x+bias; 4 f16 raw
template <int EPI, int SK, bool XCD>
__global__ __launch_bounds__(512, 2) void gemm8p_kernel(
    const f16* __restrict__ A, const f16* __restrict__ B, void* __restrict__ Cv,
    const float* __restrict__ bias, const int* __restrict__ rowCount,
    int M, int N, int K, long ldA, long ldB, long aZ, long bZ, long cZ,
    long cZ2, long biasZ)
{
  int bx = blockIdx.x, by = blockIdx.y, bz = blockIdx.z;
  if (XCD) xcd_remap(bx, by, bz);
  const int z = bz;
  const int ze = z / SK;
  const int kq = z % SK;
  if (rowCount != nullptr && (int)(by * 256) >= rowCount[ze]) return;
  __shared__ __align__(16) char lds[131072];
  const long khoff = (long)kq * K;
  A += (long)ze * aZ + khoff;  B += (long)ze * bZ + khoff;
  const int tid = threadIdx.x, w = tid >> 6, l = tid & 63;
  const int g = l >> 4, lr = l & 15;
  const long m0 = (long)by * 256, n0 = (long)bx * 256;
  const int wm = (w >> 2) * 128, wn = (w & 3) * 64;

  floatx4 acc[8][4];
#pragma unroll
  for (int i = 0; i < 8; i++)
#pragma unroll
    for (int j = 0; j < 4; j++) acc[i][j] = floatx4{0.f, 0.f, 0.f, 0.f};

  const int swzS = ((l & 3) * 8) ^ (((l >> 3) & 3) << 3);        // f16 elems
  const f16* aSrc;
  const f16* bSrc;
  long ldGl;
  {
    const int srow = w * 16 + (l >> 2);
    aSrc = A + (m0 + srow) * ldA + swzS;
    bSrc = B + (n0 + srow) * ldB + swzS;
  }
  ldGl = ldA;  // (all call sites use ldA==ldB)
  const int ldsW = w * 1024;
  const int rsw = (g * 16) ^ (((lr >> 1) & 3) << 4);
  const int afoff = wm * 64 + lr * 64 + rsw;
  const int bfoff = wn * 64 + lr * 64 + rsw;
  half8 af0, af1, af2, af3;
  half8 bf0 = half8{0}, bf1 = half8{0}, bf2 = half8{0}, bf3 = half8{0};

  STG(aSrc, 0, 0, 0, 0);
  STG(bSrc, 0, 0, 0, 1);
  STG(aSrc, 0, 1, 0, 0);
  STG(bSrc, 0, 1, 0, 1);
  STG(bSrc, 1, 0, 1, 1);
  STG(aSrc, 1, 0, 1, 0);
  STG(bSrc, 1, 1, 1, 1);
  VM10;
  __builtin_amdgcn_sched_barrier(0);
  __builtin_amdgcn_s_barrier();

  const int NI = K >> 7;          // iterations of 2 K-tiles
  for (int i = 0; i < NI - 1; i++) {
    const int t0 = 2 * i, t1 = 2 * i + 1;
    PH(0, 0, 0, 1, STG(aSrc, (t1),     1, 1, 0), VM10)   // p1
    PH(0, 0, 1, 0, STG(bSrc, (t0 + 2), 0, 0, 1), VM10)   // p2
    PH(0, 1, 0, 1, STG(aSrc, (t0 + 2), 0, 0, 0), VM10)   // p3
    PH(0, 1, 1, 0, STG(bSrc, (t0 + 2), 1, 0, 1), VM10)   // p4
    PH(1, 0, 0, 1, STG(aSrc, (t0 + 2), 1, 0, 0), VM10)   // p5
    PH(1, 0, 1, 0, STG(bSrc, (t1 + 2), 0, 1, 1), VM10)   // p6
    PH(1, 1, 0, 1, STG(aSrc, (t1 + 2), 0, 1, 0), VM10)   // p7
    PH(1, 1, 1, 0, STG(bSrc, (t1 + 2), 1, 1, 1), VM10)   // p8
  }
  {  // peeled final iteration: only p1 stages (A of last tile, kc1)
    const int t1 = 2 * (NI - 1) + 1;
    PH(0, 0, 0, 1, STG(aSrc, (t1), 1, 1, 0), VM8)
    PH(0, 0, 1, 0, NOP, NOP)
    PH(0, 1, 0, 1, NOP, VM4)
    PH(0, 1, 1, 0, NOP, NOP)
    PH(1, 0, 0, 1, NOP, VM0)
    PH(1, 0, 1, 0, NOP, NOP)
    PH(1, 1, 0, 1, NOP, NOP)
    PH(1, 1, 1, 0, NOP, NOP)
  }

  const long crow = m0 + wm + g * 4;
  const long ccol = n0 + wn + lr;
  float* c32 = (float*)Cv + (long)ze * cZ + (long)kq * cZ2;
  f16* ch = (f16*)Cv + (long)ze * cZ + (long)kq * cZ2;
#pragma unroll
  for (int mi = 0; mi < 8; mi++)
#pragma unroll
    for (int ni = 0; ni < 4; ni++)
#pragma unroll
      for (int j = 0; j < 4; j++) {
        const long r = crow + mi * 16 + j;
        const long c = ccol + ni * 16;
        float v = acc[mi][ni][j];
        if (EPI == 0) {
          c32[r * N + c] = v;
        } else if (EPI == 2) {
          v += bias[(long)ze * biasZ + c];
          // gelu_tanh(v) = v * sigmoid(1.595769*(v+0.044715 v^3)); rcp instr
          const float u2 = 1.5957691216057308f * (v + 0.044715f * v * v * v);
          const float den = 1.f + __expf(-u2);
          float sg;
          asm("v_rcp_f32 %0, %1" : "=v"(sg) : "v"(den));
          ((f16*)Cv)[(long)ze * cZ + r * N + c] = (f16)(v * sg);
        } else if (EPI == 3) {
          v += bias[(long)ze * biasZ + c];
          ((f16*)Cv)[(long)ze * cZ + r * N + c] = (f16)v;
        } else {  // 4: raw f16
          ch[r * N + c] = (f16)v;
        }
      }
}
#undef STG
#undef MROW
#undef PH
#undef VM10
#undef VM8
#undef VM4
#undef VM0
#undef NOP

// ---------------- RoPE table (double precision trig, fp32 out) --------------
__global__ void rope_table_kernel(float* __restrict__ ct, float* __restrict__ st) {
  const int i = blockIdx.x * 256 + threadIdx.x;
  if (i >= kS * 64) return;
  const int s = i >> 6, f = i & 63;
  const double freq = exp(-0.14391156831212787 * (double)f);  // ln(10000)/64
  const double ang = (double)s * freq;
  ct[i] = (float)cos(ang);
  st[i] = (float)sin(ang);
}

// ---------- RoPE apply (f16 in) + relayout to [BH][S][HD], q scaled ---------
__global__ __launch_bounds__(256) void rope_kernel(
    const f16* __restrict__ q, const f16* __restrict__ k,
    const float* __restrict__ ct, const float* __restrict__ st,
    f16* __restrict__ qr, f16* __restrict__ kr)
{
  const long t = blockIdx.x;            // b*S + s
  const int s = (int)(t & (kS - 1)), b = (int)(t >> 11);
  for (int u = threadIdx.x; u < kNH * 64; u += 256) {
    const int h = u >> 6, i = u & 63;
    const float c = ct[s * 64 + i], sn = st[s * 64 + i];
    const long src = t * kH + h * kHD + i;
    const long dst = (((long)(b * kNH + h)) * kS + s) * kHD + i;
    float x1 = (float)q[src], x2 = (float)q[src + 64];
    qr[dst]      = (f16)((x1 * c - x2 * sn) * 0.08838834764831845f);
    qr[dst + 64] = (f16)((x1 * sn + x2 * c) * 0.08838834764831845f);
    x1 = (float)k[src]; x2 = (float)k[src + 64];
    kr[dst]      = (f16)(x1 * c - x2 * sn);
    kr[dst + 64] = (f16)(x1 * sn + x2 * c);
  }
}

// ---- causal flash attention, QBLK=64, double-buffered K/V (counted vmcnt) --
__global__ __launch_bounds__(256) void attn_kernel(
    const f16* __restrict__ q_r, const f16* __restrict__ k_r,
    const f16* __restrict__ v_t, f16* __restrict__ ctx)
{
  __shared__ f16 Ks[2][64 * 128];  // [buf][key][d], swizzled
  __shared__ f16 Vs[2][128 * 64];  // [buf][d][kk], swizzled
  __shared__ f16 Ps[4][1024];      // per-wave P [16][64], swizzled
  int qt = blockIdx.x, h = blockIdx.y, b = blockIdx.z;
  xcd_remap(qt, h, b);            // contiguous qt of same (h,b) share K/V in L2
  const int bh = b * kNH + h;
  const int tid = threadIdx.x, w = tid >> 6, l = tid & 63;
  const int g = l >> 4, lr = l & 15;
  const long q0 = (long)qt * 64;
  const f16* qbase = q_r + ((long)bh * kS + q0 + w * 16 + lr) * kHD;
  half8 qf[4];
#pragma unroll
  for (int kc = 0; kc < 4; kc++) qf[kc] = *(const half8*)(qbase + kc * 32 + g * 8);
  floatx4 acc[8];
#pragma unroll
  for (int i = 0; i < 8; i++) acc[i] = floatx4{0.f, 0.f, 0.f, 0.f};
  float mrun[4], lrun[4];
#pragma unroll
  for (int j = 0; j < 4; j++) { mrun[j] = -1e30f; lrun[j] = 0.f; }
  f16* pw = Ps[w];

  // stage lane constants
  const int kRow = (w * 4) * 4 + (l >> 4);          // varies with c: +4c
  const int kSrc = (((l & 15) * 16) ^ ((((l >> 4)) & 7) << 4));  // placeholder
  // per-tile staging: 8 gload16/thread (4 K + 4 V)
  auto stage = [&](int kt, int bsel) {
    const long k0 = (long)kt * 64;
#pragma unroll
    for (int c = 0; c < 4; c++) {              // K tile
      const int cc = w * 4 + c;
      const int row = cc * 4 + (l >> 4);
      const int wb = (l & 15) * 16;
      const int src = (wb ^ ((row & 7) << 4)) >> 1;
      gload16(k_r + ((long)bh * kS + k0 + row) * kHD + src, &Ks[bsel][cc * 512]);
    }
#pragma unroll
    for (int c = 0; c < 4; c++) {              // V tile (transposed layout)
      const int cc = w * 4 + c;
      const int row = cc * 8 + (l >> 3);
      const int wb = (l & 7) * 16;
      const int src = (wb ^ ((row & 7) << 4)) >> 1;
      gload16(v_t + ((long)bh * kHD + row) * kS + k0 + src, &Vs[bsel][cc * 512]);
    }
  };
  (void)kRow; (void)kSrc;

  stage(0, 0);
  for (int kt = 0; kt <= qt; kt++) {
    const int cur = kt & 1;
    if (kt < qt) {                             // prefetch next tile, counted wait
      stage(kt + 1, cur ^ 1);
      asm volatile("s_waitcnt vmcnt(8)" ::: "memory");
    } else {
      asm volatile("s_waitcnt vmcnt(0)" ::: "memory");
    }
    __syncthreads();

    const char* kbuf = (const char*)Ks[cur];
    const char* vbuf = (const char*)Vs[cur];
    floatx4 sfr[4];
    __builtin_amdgcn_s_setprio(1);
#pragma unroll
    for (int f = 0; f < 4; f++) {              // QK^T
      floatx4 s4 = floatx4{0.f, 0.f, 0.f, 0.f};
      const int row = f * 16 + lr;
#pragma unroll
      for (int kc = 0; kc < 4; kc++) {
        const half8 kfq = *(const half8*)(kbuf + row * 256 +
                            ((kc * 64 + g * 16) ^ ((row & 7) << 4)));
        s4 = __builtin_amdgcn_mfma_f32_16x16x32_f16(qf[kc], kfq, s4, 0, 0, 0);
      }
      sfr[f] = s4;
    }
    __builtin_amdgcn_s_setprio(0);
    if (kt == qt) {                            // diagonal causal mask
#pragma unroll
      for (int f = 0; f < 4; f++) {
        const int key = kt * 64 + f * 16 + lr;
#pragma unroll
        for (int j = 0; j < 4; j++) {
          const int qrow = qt * 64 + w * 16 + g * 4 + j;
          if (key > qrow) sfr[f][j] = -1e30f;
        }
      }
    }
    float al[4];
#pragma unroll
    for (int j = 0; j < 4; j++) {              // online softmax per row
      float pm = fmaxf(fmaxf(sfr[0][j], sfr[1][j]), fmaxf(sfr[2][j], sfr[3][j]));
      pm = fmaxf(pm, __shfl_xor(pm, 1)); pm = fmaxf(pm, __shfl_xor(pm, 2));
      pm = fmaxf(pm, __shfl_xor(pm, 4)); pm = fmaxf(pm, __shfl_xor(pm, 8));
      const float mn = fmaxf(mrun[j], pm);
      al[j] = __expf(mrun[j] - mn);
      mrun[j] = mn;
      float rs = 0.f;
#pragma unroll
      for (int f = 0; f < 4; f++) {
        const float p = __expf(sfr[f][j] - mn);
        sfr[f][j] = p; rs += p;
      }
      rs += __shfl_xor(rs, 1); rs += __shfl_xor(rs, 2);
      rs += __shfl_xor(rs, 4); rs += __shfl_xor(rs, 8);
      lrun[j] = lrun[j] * al[j] + rs;
    }
#pragma unroll
    for (int nf = 0; nf < 8; nf++)
#pragma unroll
      for (int j = 0; j < 4; j++) acc[nf][j] *= al[j];
#pragma unroll
    for (int f = 0; f < 4; f++)                // P -> per-wave LDS (swizzled)
#pragma unroll
      for (int j = 0; j < 4; j++) {
        const int row = g * 4 + j;
        const int byteoff = (row * 128 + (f * 16 + lr) * 2) ^ ((row & 7) << 4);
        *(f16*)((char*)pw + byteoff) = (f16)sfr[f][j];
      }
    __builtin_amdgcn_s_setprio(1);
#pragma unroll
    for (int kc = 0; kc < 2; kc++) {           // PV
      const half8 pf = *(const half8*)((const char*)pw + lr * 128 +
                         ((kc * 64 + g * 16) ^ ((lr & 7) << 4)));
#pragma unroll
      for (int nf = 0; nf < 8; nf++) {
        const int vrow = nf * 16 + lr;
        const half8 vfr = *(const half8*)(vbuf + vrow * 128 +
                            ((kc * 64 + g * 16) ^ ((vrow & 7) << 4)));
        acc[nf] = __builtin_amdgcn_mfma_f32_16x16x32_f16(pf, vfr, acc[nf], 0, 0, 0);
      }
    }
    __builtin_amdgcn_s_setprio(0);
    __syncthreads();
  }
  const long orow = (long)b * kS + q0 + w * 16;
#pragma unroll
  for (int j = 0; j < 4; j++) {
    const float inv = 1.0f / lrun[j];
    const int r = g * 4 + j;
#pragma unroll
    for (int nf = 0; nf < 8; nf++)
      ctx[(orow + r) * kH + h * kHD + nf * 16 + lr] = (f16)(acc[nf][j] * inv);
  }
}

// -- residual 1: h2 = hidden + ls*((P0+P1) * sigmoid(g+bg)); f16 P and g -----
__global__ __launch_bounds__(256) void combine1_kernel(
    const float* __restrict__ hid, const f16* __restrict__ a0,
    const f16* __restrict__ a1, const f16* __restrict__ glin,
    const float* __restrict__ bg, const float* __restrict__ ls,
    float* __restrict__ out)
{
  const long i = (long)blockIdx.x * 256 + threadIdx.x;
  const float4 hv = ((const float4*)hid)[i];
  const half4 av = ((const half4*)a0)[i];
  const half4 aw = ((const half4*)a1)[i];
  const half4 gv = ((const half4*)glin)[i];
  const int c = (int)(i & 511);
  const float4 lv = ((const float4*)ls)[c];
  const float4 bv = ((const float4*)bg)[c];
  float4 o;
  o.x = hv.x + lv.x * ((float)av[0] + (float)aw[0]) / (1.f + __expf(-((float)gv[0] + bv.x)));
  o.y = hv.y + lv.y * ((float)av[1] + (float)aw[1]) / (1.f + __expf(-((float)gv[1] + bv.y)));
  o.z = hv.z + lv.z * ((float)av[2] + (float)aw[2]) / (1.f + __expf(-((float)gv[2] + bv.z)));
  o.w = hv.w + lv.w * ((float)av[3] + (float)aw[3]) / (1.f + __expf(-((float)gv[3] + bv.w)));
  ((float4*)out)[i] = o;
}

// ---------------- router: logits(fp32) -> softmax -> top2 -> gates ----------
__global__ __launch_bounds__(256) void router_kernel(
    const float* __restrict__ x, const float* __restrict__ rw,
    int* __restrict__ eidx, float* __restrict__ gates)
{
  const int t = blockIdx.x * 4 + (threadIdx.x >> 6);
  const int l = threadIdx.x & 63;
  const float* xr = x + (long)t * kH;
  float a[8] = {0.f, 0.f, 0.f, 0.f, 0.f, 0.f, 0.f, 0.f};
  for (int it = 0; it < kH / 64; it++) {
    const float xv = xr[it * 64 + l];
    const float* r = rw + (long)(it * 64 + l) * kE;
#pragma unroll
    for (int e = 0; e < 8; e++) a[e] += xv * r[e];
  }
#pragma unroll
  for (int e = 0; e < 8; e++)
#pragma unroll
    for (int m = 1; m < 64; m <<= 1) a[e] += __shfl_xor(a[e], m);
  if (l == 0) {
    float mx = a[0];
#pragma unroll
    for (int e = 1; e < 8; e++) mx = fmaxf(mx, a[e]);
    float p[8];
#pragma unroll
    for (int e = 0; e < 8; e++) p[e] = __expf(a[e] - mx);
    int i1 = 0; float v1 = p[0];
#pragma unroll
    for (int e = 1; e < 8; e++) if (p[e] > v1) { v1 = p[e]; i1 = e; }
    int i2 = -1; float v2 = -1.f;
#pragma unroll
    for (int e = 0; e < 8; e++) if (e != i1 && p[e] > v2) { v2 = p[e]; i2 = e; }
    const float inv = 1.f / (v1 + v2);
    eidx[t * 2] = i1; eidx[t * 2 + 1] = i2;
    gates[t * 2] = v1 * inv; gates[t * 2 + 1] = v2 * inv;
  }
}

// ---------------- deterministic capacity scan (single wave) -----------------
__global__ void scan_kernel(const int* __restrict__ eidx, int* __restrict__ slot,
                            int* __restrict__ counts)
{
  const int l = threadIdx.x;
  int base[8] = {0, 0, 0, 0, 0, 0, 0, 0};
  const unsigned long long lt = (1ull << l) - 1ull;
  for (int it = 0; it < kTK / 64; it++) {
    const int i = it * 64 + l;
    const int e = eidx[i];
    int mypos = 0;
#pragma unroll
    for (int ex = 0; ex < 8; ex++) {
      const unsigned long long mk = __ballot(e == ex);
      if (e == ex) mypos = base[ex] + __popcll(mk & lt);
      base[ex] += __popcll(mk);
    }
    slot[i] = (mypos < kCAP) ? e * kCAP + mypos : -1;
  }
  if (l == 0) {
#pragma unroll
    for (int ex = 0; ex < 8; ex++) counts[ex] = min(base[ex], kCAP);
  }
}

// ---------------- scatter tokens into expert buffers ------------------------
__global__ __launch_bounds__(256) void scatter_kernel(
    const f16* __restrict__ xh, const int* __restrict__ slot, f16* __restrict__ buf)
{
  const int i = blockIdx.x;
  const int s = slot[i];
  if (s < 0) return;
  const long t = i >> 1;
  ((half8*)(buf + (long)s * kH))[threadIdx.x] =
      ((const half8*)(xh + t * kH))[threadIdx.x];
}

// --- final combine: sum 4 f16 split-K partials + bias + gate + residual -----
__global__ __launch_bounds__(256) void combine2_kernel(
    const float* __restrict__ hid2, const f16* __restrict__ P,
    const int* __restrict__ slot, const float* __restrict__ gates,
    const float* __restrict__ b2, const float* __restrict__ ls,
    float* __restrict__ out, long pS)
{
  const int t = blockIdx.x;
  const int c = threadIdx.x * 8;
  float m[8] = {0.f, 0.f, 0.f, 0.f, 0.f, 0.f, 0.f, 0.f};
#pragma unroll
  for (int ks = 0; ks < 2; ks++) {
    const int s = slot[t * 2 + ks];
    if (s < 0) continue;
    const float gte = gates[t * 2 + ks];
    const int e = s / kCAP;
    const long ro = (long)s * kH + c;
    float acc8[8];
    const float4 ba = *(const float4*)&b2[e * kH + c];
    const float4 bb = *(const float4*)&b2[e * kH + c + 4];
    acc8[0] = ba.x; acc8[1] = ba.y; acc8[2] = ba.z; acc8[3] = ba.w;
    acc8[4] = bb.x; acc8[5] = bb.y; acc8[6] = bb.z; acc8[7] = bb.w;
#pragma unroll
    for (int q = 0; q < 4; q++) {
      const half8 p = *(const half8*)&P[q * pS + ro];
#pragma unroll
      for (int j = 0; j < 8; j++) acc8[j] += (float)p[j];
    }
#pragma unroll
    for (int j = 0; j < 8; j++) m[j] += gte * acc8[j];
  }
  const float* hp = hid2 + (long)t * kH + c;
  float* op = out + (long)t * kH + c;
#pragma unroll
  for (int j = 0; j < 8; j++) op[j] = hp[j] + ls[c + j] * m[j];
}

// ============================================================================
extern "C" void kernel_launch(void* const* d_in, const int* in_sizes, int n_in,
                              void* d_out, int out_size, void* d_ws, size_t ws_size,
                              hipStream_t stream)
{
  (void)in_sizes; (void)n_in;
  const float* hidden   = (const float*)d_in[0];
  const float* ln1s     = (const float*)d_in[2];
  const float* ln1b     = (const float*)d_in[3];
  const float* ln2s     = (const float*)d_in[4];
  const float* ln2b     = (const float*)d_in[5];
  const float* Wq       = (const float*)d_in[6];
  const float* Wk       = (const float*)d_in[7];
  const float* Wv       = (const float*)d_in[8];
  const float* Wo       = (const float*)d_in[9];
  const float* Wg       = (const float*)d_in[10];
  const float* bg       = (const float*)d_in[11];
  const float* ls_attn  = (const float*)d_in[12];
  const float* ls_moe   = (const float*)d_in[13];
  const float* router_w = (const float*)d_in[14];
  const float* W1       = (const float*)d_in[15];
  const float* b1       = (const float*)d_in[16];
  const float* W2       = (const float*)d_in[17];
  const float* b2       = (const float*)d_in[18];

  char* ws = (char*)d_ws;
  size_t off = 0;
  auto take = [&](size_t b) { size_t r = off; off += (b + 255) & ~(size_t)255; return r; };
  const size_t o_wT   = take(5ULL * kH * kH * 2);              // WqT..WgT,WoT f16
  const size_t o_w1t  = take((size_t)kE * kF * kH * 2);        // W1^T f16
  const size_t o_w2t  = take((size_t)kE * kH * kF * 2);        // W2^T f16
  const size_t o_xn   = take((size_t)kT * kH * 2);             // LN1 out f16
  const size_t o_qkvg = take(4ULL * kT * kH * 4);              // qkvg region
  const size_t o_tab  = take(2ULL * kS * 64 * 4);              // rope cos/sin
  const size_t o_qr   = take(3ULL * kT * kH * 2);              // qr, kr, vt f16
  const size_t o_ctx  = take((size_t)kT * kH * 2);             // attn out f16
  const size_t o_h2   = take((size_t)kT * kH * 4);             // residual fp32
  const size_t o_sm   = take(1 << 20);                         // routing small
  const size_t o_hmid = take((size_t)kE * kCAP * kF * 2);      // expert mid f16
  if (off > ws_size) { hipMemsetAsync(d_out, 0xFF, (size_t)out_size * 4, stream); return; }

  f16* wT    = (f16*)(ws + o_wT);
  f16* w1t   = (f16*)(ws + o_w1t);
  f16* w2t   = (f16*)(ws + o_w2t);
  f16* xn    = (f16*)(ws + o_xn);
  float* tabc = (float*)(ws + o_tab);
  float* tabs = tabc + (size_t)kS * 64;
  f16* qr  = (f16*)(ws + o_qr);
  f16* kr  = qr + (size_t)kT * kH;
  f16* vt  = kr + (size_t)kT * kH;
  f16* ctx = (f16*)(ws + o_ctx);
  float* h2 = (float*)(ws + o_h2);
  int* eidx    = (int*)(ws + o_sm);
  float* gates = (float*)(ws + o_sm + 65536);
  int* slot    = (int*)(ws + o_sm + 131072);
  int* counts  = (int*)(ws + o_sm + 196608);
  f16* hmid = (f16*)(ws + o_hmid);

  // qkvg region layout (f16 qkvg outputs + temporal aliases), S2 = kT*kH*2 B
  const size_t S2 = (size_t)kT * kH * 2;
  char* R = ws + o_qkvg;
  f16* qh = (f16*)(R + 0 * S2);          // dead after rope
  f16* kh = (f16*)(R + 1 * S2);          // dead after rope
  f16* vh = (f16*)(R + 2 * S2);          // dead after V-transpose
  f16* gh = (f16*)(R + 3 * S2);          // dead after combine1
  float* x2f = (float*)(R + 4 * S2);     // LN2 fp32 (router input)
  f16* x2h   = (f16*)(R + 6 * S2);       // LN2 f16 (expert input)
  f16* woPh  = (f16*)(R + 0 * S2);       // Wo split-K partials (2x S2), over q/k
  f16* buf  = qr;                        // expert input buffers (qr region dead)
  // MoE GEMM2 split-K=4 f16 partials: w1t region (dead after GEMM1), 4x42MB
  f16* Ph = (f16*)(ws + o_w1t);
  const long pS = (long)kE * kCAP * kH;  // stride between partial buffers

  const long HH = (long)kH * kH;

  // 1. LN1 + batched small weight transposes
  ln_kernel<<<kT, 256, 0, stream>>>(hidden, ln1s, ln1b, xn, nullptr);
  transpose_cvt5<<<dim3(32, 32, 5), 256, 0, stream>>>(Wq, Wk, Wv, Wg, Wo, wT);
  // 2. fused QKV+gate GEMMs, f16 outputs; XCD remap on (B fits L2)
  gemm8p_kernel<4, 1, true><<<dim3(kH / 256, kT / 256, 4), 512, 0, stream>>>(
      xn, wT, qh, nullptr, nullptr, kT, kH, kH, kH, kH,
      0L, HH, (long)kT * kH, 0L, 0L);
  // 3. RoPE (f16 inputs)
  rope_table_kernel<<<(kS * 64 + 255) / 256, 256, 0, stream>>>(tabc, tabs);
  rope_kernel<<<kT, 256, 0, stream>>>(qh, kh, tabc, tabs, qr, kr);
  // 4. V transpose to [BH][HD][S] (f16 -> f16)
  for (int b = 0; b < kB; b++)
    transpose_f16<<<dim3(kHD / 64, kS / 64, kNH), 256, 0, stream>>>(
        vh + (size_t)b * kS * kH, vt + (size_t)b * kNH * kHD * kS,
        kH, kS, 128L, (long)kHD * kS);
  // 5. attention, QBLK=64, double-buffered K/V (grid 1024 % 8 == 0)
  attn_kernel<<<dim3(kS / 64, kNH, kB), 256, 0, stream>>>(qr, kr, vt, ctx);
  // 6. Wo GEMM, split-K=2, f16 partials into the dead q/k slots
  gemm8p_kernel<4, 2, true><<<dim3(kH / 256, kT / 256, 2), 512, 0, stream>>>(
      ctx, wT + 4 * HH, woPh, nullptr, nullptr, kT, kH, 1024, kH, kH,
      0L, 0L, 0L, (long)kT * kH, 0L);
  // 7. gated residual (sums the two Wo f16 partials, f16 gate)
  combine1_kernel<<<(kT * kH / 4) / 256, 256, 0, stream>>>(
      hidden, woPh, woPh + (size_t)kT * kH, gh, bg, ls_attn, h2);
  // 8. LN2 (f16 for experts, fp32 for router)
  ln_kernel<<<kT, 256, 0, stream>>>(h2, ln2s, ln2b, x2h, x2f);
  // 9-11. routing
  router_kernel<<<kT / 4, 256, 0, stream>>>(x2f, router_w, eidx, gates);
  scan_kernel<<<1, 64, 0, stream>>>(eidx, slot, counts);
  scatter_kernel<<<kTK, 256, 0, stream>>>(x2h, slot, buf);
  // 12. W1 transpose here: w1t L3-warm for GEMM1
  transpose_cvt<<<dim3(kF / 64, kH / 64, kE), 256, 0, stream>>>(
      W1, w1t, kF, kH, (long)kH * kF, (long)kF * kH);
  // 13. expert GEMM1 + gelu -- default order, no remap (r5/r8)
  gemm8p_kernel<2, 1, false><<<dim3(kF / 256, kCAP / 256, kE), 512, 0, stream>>>(
      buf, w1t, hmid, b1, counts, kCAP, kF, kH, kH, kH,
      (long)kCAP * kH, (long)kF * kH, (long)kCAP * kF, 0L, (long)kF);
  // 14. W2 transpose here: w2t L3-warm for GEMM2
  transpose_cvt<<<dim3(kH / 64, kF / 64, kE), 256, 0, stream>>>(
      W2, w2t, kH, kF, (long)kF * kH, (long)kH * kF);
  // 15. expert GEMM2, split-K=4, f16 partials
  gemm8p_kernel<4, 4, false><<<dim3(kH / 256, kCAP / 256, 4 * kE), 512, 0, stream>>>(
      hmid, w2t, Ph, nullptr, counts, kCAP, kH, 2048, kF, kF,
      (long)kCAP * kF, (long)kH * kF, (long)kCAP * kH, pS, 0L);
  // 16. final combine (adds 4 partials + b2, gates, residual)
  combine2_kernel<<<kT, 256, 0, stream>>>(
      h2, Ph, slot, gates, b2, ls_moe, (float*)d_out, pS);
}

// Round 14
// 1499.163 us; speedup vs baseline: 1.0038x; 1.0038x over previous
//
#include <hip/hip_runtime.h>
#include <hip/hip_fp16.h>

typedef _Float16 f16;
typedef _Float16 half4 __attribute__((ext_vector_type(4)));
typedef _Float16 half8 __attribute__((ext_vector_type(8)));
typedef float floatx4 __attribute__((ext_vector_type(4)));

constexpr int kH  = 2048;
constexpr int kS  = 2048;
constexpr int kB  = 2;
constexpr int kT  = kB * kS;   // 4096 tokens
constexpr int kNH = 16;
constexpr int kHD = 128;
constexpr int kE  = 8;
constexpr int kF  = 8192;
constexpr int kCAP = 1280;     // ceil(T*K/E*1.25)
constexpr int kTK = kT * 2;

__device__ __forceinline__ void gload16(const void* g, void* lds_) {
  __builtin_amdgcn_global_load_lds((const __attribute__((address_space(1))) void*)g,
                                   (__attribute__((address_space(3))) void*)lds_,
                                   16, 0, 0);
}

// XCD-chunked bijective remap (requires nwg % 8 == 0). Use ONLY for qkvg and
// attn (operands fit L2). NOT for MoE GEMMs (r5: L3 thrash; r8: SWAPXY also
// hurts -- default N-fastest order is best there). r11: 128^2 occupancy-2
// tile also worse (2x B-traffic + half the MFMA per phase) -- 256^2 stays.
// r13: attn K/V double-buffer neutral (LDS 40->72KB halves blocks/CU; TLP
// already hides the vmcnt drain at 4 blocks/CU) -- single-buffer stays.
__device__ __forceinline__ void xcd_remap(int& bx, int& by, int& bz) {
  const int gx = gridDim.x, gy = gridDim.y;
  const int nwg = gx * gy * gridDim.z;
  int L = (bz * gy + by) * gx + bx;
  L = (L & 7) * (nwg >> 3) + (L >> 3);
  bz = L / (gx * gy);
  const int r = L - bz * gx * gy;
  by = r / gx;  bx = r - by * gx;
}

// ---------------- transpose + fp32->fp16 convert: src[K][N] -> dst[N][K] ----
__global__ __launch_bounds__(256) void transpose_cvt(
    const float* __restrict__ src, f16* __restrict__ dst,
    int ldS, int ldD, long sZ, long dZ)
{
  __shared__ float tile[64][65];
  src += (long)blockIdx.z * sZ;
  dst += (long)blockIdx.z * dZ;
  const int kb = blockIdx.y * 64, nb = blockIdx.x * 64;
  const int tx = threadIdx.x & 15, ty = threadIdx.x >> 4;
#pragma unroll
  for (int i = 0; i < 4; i++) {
    const int r = ty + i * 16;
    const float4 v = *(const float4*)&src[(long)(kb + r) * ldS + nb + tx * 4];
    tile[r][tx * 4 + 0] = v.x; tile[r][tx * 4 + 1] = v.y;
    tile[r][tx * 4 + 2] = v.z; tile[r][tx * 4 + 3] = v.w;
  }
  __syncthreads();
  const int tx8 = threadIdx.x & 7, ty32 = threadIdx.x >> 3;
#pragma unroll
  for (int i = 0; i < 2; i++) {
    const int n = ty32 + i * 32;
    union { f16 h[8]; float4 v; } pk;
#pragma unroll
    for (int j = 0; j < 8; j++) pk.h[j] = (f16)tile[tx8 * 8 + j][n];
    *(float4*)&dst[(long)(nb + n) * ldD + kb + tx8 * 8] = pk.v;
  }
}

// ---- batched 2048x2048 transpose-convert of the 5 attention weights --------
__global__ __launch_bounds__(256) void transpose_cvt5(
    const float* __restrict__ s0, const float* __restrict__ s1,
    const float* __restrict__ s2, const float* __restrict__ s3,
    const float* __restrict__ s4, f16* __restrict__ dst)
{
  __shared__ float tile[64][65];
  const float* src;
  switch (blockIdx.z) {
    case 0: src = s0; break;
    case 1: src = s1; break;
    case 2: src = s2; break;
    case 3: src = s3; break;
    default: src = s4; break;
  }
  dst += (long)blockIdx.z * kH * kH;
  const int kb = blockIdx.y * 64, nb = blockIdx.x * 64;
  const int tx = threadIdx.x & 15, ty = threadIdx.x >> 4;
#pragma unroll
  for (int i = 0; i < 4; i++) {
    const int r = ty + i * 16;
    const float4 v = *(const float4*)&src[(long)(kb + r) * kH + nb + tx * 4];
    tile[r][tx * 4 + 0] = v.x; tile[r][tx * 4 + 1] = v.y;
    tile[r][tx * 4 + 2] = v.z; tile[r][tx * 4 + 3] = v.w;
  }
  __syncthreads();
  const int tx8 = threadIdx.x & 7, ty32 = threadIdx.x >> 3;
#pragma unroll
  for (int i = 0; i < 2; i++) {
    const int n = ty32 + i * 32;
    union { f16 h[8]; float4 v; } pk;
#pragma unroll
    for (int j = 0; j < 8; j++) pk.h[j] = (f16)tile[tx8 * 8 + j][n];
    *(float4*)&dst[(long)(nb + n) * kH + kb + tx8 * 8] = pk.v;
  }
}

// ---------------- f16 -> f16 transpose (V relayout) -------------------------
__global__ __launch_bounds__(256) void transpose_f16(
    const f16* __restrict__ src, f16* __restrict__ dst,
    int ldS, int ldD, long sZ, long dZ)
{
  __shared__ f16 tile[64][80];
  src += (long)blockIdx.z * sZ;
  dst += (long)blockIdx.z * dZ;
  const int kb = blockIdx.y * 64, nb = blockIdx.x * 64;
  const int tx = threadIdx.x & 7, ty = threadIdx.x >> 3;  // 8 x 32
#pragma unroll
  for (int i = 0; i < 2; i++) {
    const int r = ty + i * 32;
    *(half8*)&tile[r][tx * 8] =
        *(const half8*)&src[(long)(kb + r) * ldS + nb + tx * 8];
  }
  __syncthreads();
#pragma unroll
  for (int i = 0; i < 2; i++) {
    const int n = ty + i * 32;
    union { f16 h[8]; float4 v; } pk;
#pragma unroll
    for (int j = 0; j < 8; j++) pk.h[j] = tile[tx * 8 + j][n];
    *(float4*)&dst[(long)(nb + n) * ldD + kb + tx * 8] = pk.v;
  }
}

// ---------------- layernorm: one block (256 thr) per row of 2048 ------------
__global__ __launch_bounds__(256) void ln_kernel(
    const float* __restrict__ x, const float* __restrict__ sc,
    const float* __restrict__ bi, f16* __restrict__ o16, float* __restrict__ o32)
{
  const long row = blockIdx.x;
  const float* xr = x + row * kH;
  const int t = threadIdx.x;
  const float4 u = ((const float4*)xr)[t * 2];
  const float4 v = ((const float4*)xr)[t * 2 + 1];
  float s = u.x + u.y + u.z + u.w + v.x + v.y + v.z + v.w;
  float q = u.x*u.x + u.y*u.y + u.z*u.z + u.w*u.w + v.x*v.x + v.y*v.y + v.z*v.z + v.w*v.w;
#pragma unroll
  for (int m = 1; m < 64; m <<= 1) { s += __shfl_xor(s, m); q += __shfl_xor(q, m); }
  __shared__ float red_s[4], red_q[4];
  const int w = t >> 6, l = t & 63;
  if (l == 0) { red_s[w] = s; red_q[w] = q; }
  __syncthreads();
  s = red_s[0] + red_s[1] + red_s[2] + red_s[3];
  q = red_q[0] + red_q[1] + red_q[2] + red_q[3];
  const float mean = s * (1.f / kH);
  const float var = q * (1.f / kH) - mean * mean;
  const float rstd = rsqrtf(var + 1e-5f);
  const int c = t * 8;
  const float vals[8] = {u.x, u.y, u.z, u.w, v.x, v.y, v.z, v.w};
#pragma unroll
  for (int j = 0; j < 8; j++) {
    const float y = (vals[j] - mean) * rstd * sc[c + j] + bi[c + j];
    o16[row * kH + c + j] = (f16)y;
    if (o32 != nullptr) o32[row * kH + c + j] = y;
  }
}

// ---------------- 256x256 8-phase pipelined GEMM ----------------------------
// C[M][N] = A[M][K] * B^T[N][K], f16 in / f32 acc. 8 waves (2Mx4N), per-wave
// C = 128x64. K-tile = 64 (2 kc-halves of 32). LDS = 8 units of 16KB.
// Per-phase vmcnt(10) retires the unit staged 6 phases (~1200cy) ago.
// SK-way split-K: z = expert*SK + kq; partials written cZ2 apart.
#define STG(SRC, TILE, KC, PAR, MAT) { \
  const f16* s_ = (SRC) + (long)(TILE) * 64 + (KC) * 32; \
  char* d_ = lds + ((PAR) * 65536 + (MAT) * 32768 + (KC) * 16384) + ldsW; \
  gload16(s_, d_); \
  gload16(s_ + 128 * ldGl, d_ + 8192); }

#define MROW(MH, MM, AF) \
  acc[(MH)*4+(MM)][0] = __builtin_amdgcn_mfma_f32_16x16x32_f16(AF, bf0, acc[(MH)*4+(MM)][0], 0, 0, 0); \
  acc[(MH)*4+(MM)][1] = __builtin_amdgcn_mfma_f32_16x16x32_f16(AF, bf1, acc[(MH)*4+(MM)][1], 0, 0, 0); \
  acc[(MH)*4+(MM)][2] = __builtin_amdgcn_mfma_f32_16x16x32_f16(AF, bf2, acc[(MH)*4+(MM)][2], 0, 0, 0); \
  acc[(MH)*4+(MM)][3] = __builtin_amdgcn_mfma_f32_16x16x32_f16(AF, bf3, acc[(MH)*4+(MM)][3], 0, 0, 0);

#define PH(PAR, KC, MH, RB, STAGE_STMT, VM_STMT) { \
  const char* au_ = lds + ((PAR) * 65536 + (KC) * 16384); \
  const char* bu_ = lds + ((PAR) * 65536 + 32768 + (KC) * 16384); \
  af0 = *(const half8*)(au_ + afoff + (MH) * 4096 +    0); \
  af1 = *(const half8*)(au_ + afoff + (MH) * 4096 + 1024); \
  af2 = *(const half8*)(au_ + afoff + (MH) * 4096 + 2048); \
  af3 = *(const half8*)(au_ + afoff + (MH) * 4096 + 3072); \
  if (RB) { \
    bf0 = *(const half8*)(bu_ + bfoff +    0); \
    bf1 = *(const half8*)(bu_ + bfoff + 1024); \
    bf2 = *(const half8*)(bu_ + bfoff + 2048); \
    bf3 = *(const half8*)(bu_ + bfoff + 3072); \
  } \
  STAGE_STMT; \
  VM_STMT; \
  __builtin_amdgcn_sched_barrier(0); \
  __builtin_amdgcn_s_barrier(); \
  asm volatile("s_waitcnt lgkmcnt(0)" ::: "memory"); \
  __builtin_amdgcn_sched_barrier(0); \
  __builtin_amdgcn_s_setprio(1); \
  MROW(MH, 0, af0) MROW(MH, 1, af1) MROW(MH, 2, af2) MROW(MH, 3, af3) \
  __builtin_amdgcn_s_setprio(0); }

#define VM10 asm volatile("s_waitcnt vmcnt(10)" ::: "memory")
#define VM8  asm volatile("s_waitcnt vmcnt(8)" ::: "memory")
#define VM4  asm volatile("s_waitcnt vmcnt(4)" ::: "memory")
#define VM0  asm volatile("s_waitcnt vmcnt(0)" ::: "memory")
#define NOP (void)0

// EPI: 0 f32 store; 2 f16 gelu(x+bias); 3 f16 x+bias; 4 f16 raw
template <int EPI, int SK, bool XCD>
__global__ __launch_bounds__(512, 2) void gemm8p_kernel(
    const f16* __restrict__ A, const f16* __restrict__ B, void* __restrict__ Cv,
    const float* __restrict__ bias, const int* __restrict__ rowCount,
    int M, int N, int K, long ldA, long ldB, long aZ, long bZ, long cZ,
    long cZ2, long biasZ)
{
  int bx = blockIdx.x, by = blockIdx.y, bz = blockIdx.z;
  if (XCD) xcd_remap(bx, by, bz);
  const int z = bz;
  const int ze = z / SK;
  const int kq = z % SK;
  if (rowCount != nullptr && (int)(by * 256) >= rowCount[ze]) return;
  __shared__ __align__(16) char lds[131072];
  const long khoff = (long)kq * K;
  A += (long)ze * aZ + khoff;  B += (long)ze * bZ + khoff;
  const int tid = threadIdx.x, w = tid >> 6, l = tid & 63;
  const int g = l >> 4, lr = l & 15;
  const long m0 = (long)by * 256, n0 = (long)bx * 256;
  const int wm = (w >> 2) * 128, wn = (w & 3) * 64;

  floatx4 acc[8][4];
#pragma unroll
  for (int i = 0; i < 8; i++)
#pragma unroll
    for (int j = 0; j < 4; j++) acc[i][j] = floatx4{0.f, 0.f, 0.f, 0.f};

  const int swzS = ((l & 3) * 8) ^ (((l >> 3) & 3) << 3);        // f16 elems
  const f16* aSrc;
  const f16* bSrc;
  long ldGl;
  {
    const int srow = w * 16 + (l >> 2);
    aSrc = A + (m0 + srow) * ldA + swzS;
    bSrc = B + (n0 + srow) * ldB + swzS;
  }
  ldGl = ldA;  // (all call sites use ldA==ldB)
  const int ldsW = w * 1024;
  const int rsw = (g * 16) ^ (((lr >> 1) & 3) << 4);
  const int afoff = wm * 64 + lr * 64 + rsw;
  const int bfoff = wn * 64 + lr * 64 + rsw;
  half8 af0, af1, af2, af3;
  half8 bf0 = half8{0}, bf1 = half8{0}, bf2 = half8{0}, bf3 = half8{0};

  STG(aSrc, 0, 0, 0, 0);
  STG(bSrc, 0, 0, 0, 1);
  STG(aSrc, 0, 1, 0, 0);
  STG(bSrc, 0, 1, 0, 1);
  STG(bSrc, 1, 0, 1, 1);
  STG(aSrc, 1, 0, 1, 0);
  STG(bSrc, 1, 1, 1, 1);
  VM10;
  __builtin_amdgcn_sched_barrier(0);
  __builtin_amdgcn_s_barrier();

  const int NI = K >> 7;          // iterations of 2 K-tiles
  for (int i = 0; i < NI - 1; i++) {
    const int t0 = 2 * i, t1 = 2 * i + 1;
    PH(0, 0, 0, 1, STG(aSrc, (t1),     1, 1, 0), VM10)   // p1
    PH(0, 0, 1, 0, STG(bSrc, (t0 + 2), 0, 0, 1), VM10)   // p2
    PH(0, 1, 0, 1, STG(aSrc, (t0 + 2), 0, 0, 0), VM10)   // p3
    PH(0, 1, 1, 0, STG(bSrc, (t0 + 2), 1, 0, 1), VM10)   // p4
    PH(1, 0, 0, 1, STG(aSrc, (t0 + 2), 1, 0, 0), VM10)   // p5
    PH(1, 0, 1, 0, STG(bSrc, (t1 + 2), 0, 1, 1), VM10)   // p6
    PH(1, 1, 0, 1, STG(aSrc, (t1 + 2), 0, 1, 0), VM10)   // p7
    PH(1, 1, 1, 0, STG(bSrc, (t1 + 2), 1, 1, 1), VM10)   // p8
  }
  {  // peeled final iteration: only p1 stages (A of last tile, kc1)
    const int t1 = 2 * (NI - 1) + 1;
    PH(0, 0, 0, 1, STG(aSrc, (t1), 1, 1, 0), VM8)
    PH(0, 0, 1, 0, NOP, NOP)
    PH(0, 1, 0, 1, NOP, VM4)
    PH(0, 1, 1, 0, NOP, NOP)
    PH(1, 0, 0, 1, NOP, VM0)
    PH(1, 0, 1, 0, NOP, NOP)
    PH(1, 1, 0, 1, NOP, NOP)
    PH(1, 1, 1, 0, NOP, NOP)
  }

  const long crow = m0 + wm + g * 4;
  const long ccol = n0 + wn + lr;
  float* c32 = (float*)Cv + (long)ze * cZ + (long)kq * cZ2;
  f16* ch = (f16*)Cv + (long)ze * cZ + (long)kq * cZ2;
#pragma unroll
  for (int mi = 0; mi < 8; mi++)
#pragma unroll
    for (int ni = 0; ni < 4; ni++)
#pragma unroll
      for (int j = 0; j < 4; j++) {
        const long r = crow + mi * 16 + j;
        const long c = ccol + ni * 16;
        float v = acc[mi][ni][j];
        if (EPI == 0) {
          c32[r * N + c] = v;
        } else if (EPI == 2) {
          v += bias[(long)ze * biasZ + c];
          // gelu_tanh(v) = v * sigmoid(1.595769*(v+0.044715 v^3)); rcp instr
          const float u2 = 1.5957691216057308f * (v + 0.044715f * v * v * v);
          const float den = 1.f + __expf(-u2);
          float sg;
          asm("v_rcp_f32 %0, %1" : "=v"(sg) : "v"(den));
          ((f16*)Cv)[(long)ze * cZ + r * N + c] = (f16)(v * sg);
        } else if (EPI == 3) {
          v += bias[(long)ze * biasZ + c];
          ((f16*)Cv)[(long)ze * cZ + r * N + c] = (f16)v;
        } else {  // 4: raw f16
          ch[r * N + c] = (f16)v;
        }
      }
}
#undef STG
#undef MROW
#undef PH
#undef VM10
#undef VM8
#undef VM4
#undef VM0
#undef NOP

// ---------------- RoPE table (double precision trig, fp32 out) --------------
__global__ void rope_table_kernel(float* __restrict__ ct, float* __restrict__ st) {
  const int i = blockIdx.x * 256 + threadIdx.x;
  if (i >= kS * 64) return;
  const int s = i >> 6, f = i & 63;
  const double freq = exp(-0.14391156831212787 * (double)f);  // ln(10000)/64
  const double ang = (double)s * freq;
  ct[i] = (float)cos(ang);
  st[i] = (float)sin(ang);
}

// ---------- RoPE apply (f16 in) + relayout to [BH][S][HD], q scaled ---------
__global__ __launch_bounds__(256) void rope_kernel(
    const f16* __restrict__ q, const f16* __restrict__ k,
    const float* __restrict__ ct, const float* __restrict__ st,
    f16* __restrict__ qr, f16* __restrict__ kr)
{
  const long t = blockIdx.x;            // b*S + s
  const int s = (int)(t & (kS - 1)), b = (int)(t >> 11);
  for (int u = threadIdx.x; u < kNH * 64; u += 256) {
    const int h = u >> 6, i = u & 63;
    const float c = ct[s * 64 + i], sn = st[s * 64 + i];
    const long src = t * kH + h * kHD + i;
    const long dst = (((long)(b * kNH + h)) * kS + s) * kHD + i;
    float x1 = (float)q[src], x2 = (float)q[src + 64];
    qr[dst]      = (f16)((x1 * c - x2 * sn) * 0.08838834764831845f);
    qr[dst + 64] = (f16)((x1 * sn + x2 * c) * 0.08838834764831845f);
    x1 = (float)k[src]; x2 = (float)k[src + 64];
    kr[dst]      = (f16)(x1 * c - x2 * sn);
    kr[dst + 64] = (f16)(x1 * sn + x2 * c);
  }
}

// ---------------- causal flash attention, QBLK=64 + setprio (T5) ------------
__global__ __launch_bounds__(256) void attn_kernel(
    const f16* __restrict__ q_r, const f16* __restrict__ k_r,
    const f16* __restrict__ v_t, f16* __restrict__ ctx)
{
  __shared__ f16 Ks[64 * 128];    // [key][d], swizzled
  __shared__ f16 Vs[128 * 64];    // [d][kk], swizzled
  __shared__ f16 Ps[4][1024];     // per-wave P [16][64], swizzled
  int qt = blockIdx.x, h = blockIdx.y, b = blockIdx.z;
  xcd_remap(qt, h, b);            // contiguous qt of same (h,b) share K/V in L2
  const int bh = b * kNH + h;
  const int tid = threadIdx.x, w = tid >> 6, l = tid & 63;
  const int g = l >> 4, lr = l & 15;
  const long q0 = (long)qt * 64;
  const f16* qbase = q_r + ((long)bh * kS + q0 + w * 16 + lr) * kHD;
  half8 qf[4];
#pragma unroll
  for (int kc = 0; kc < 4; kc++) qf[kc] = *(const half8*)(qbase + kc * 32 + g * 8);
  floatx4 acc[8];
#pragma unroll
  for (int i = 0; i < 8; i++) acc[i] = floatx4{0.f, 0.f, 0.f, 0.f};
  float mrun[4], lrun[4];
#pragma unroll
  for (int j = 0; j < 4; j++) { mrun[j] = -1e30f; lrun[j] = 0.f; }
  f16* pw = Ps[w];

  for (int kt = 0; kt <= qt; kt++) {
    const long k0 = (long)kt * 64;
#pragma unroll
    for (int c = 0; c < 4; c++) {              // K tile
      const int cc = w * 4 + c;
      const int row = cc * 4 + (l >> 4);
      const int wb = (l & 15) * 16;
      const int src = (wb ^ ((row & 7) << 4)) >> 1;
      gload16(k_r + ((long)bh * kS + k0 + row) * kHD + src, Ks + cc * 512);
    }
#pragma unroll
    for (int c = 0; c < 4; c++) {              // V tile (transposed layout)
      const int cc = w * 4 + c;
      const int row = cc * 8 + (l >> 3);
      const int wb = (l & 7) * 16;
      const int src = (wb ^ ((row & 7) << 4)) >> 1;
      gload16(v_t + ((long)bh * kHD + row) * kS + k0 + src, Vs + cc * 512);
    }
    asm volatile("s_waitcnt vmcnt(0)" ::: "memory");
    __syncthreads();

    floatx4 sfr[4];
    __builtin_amdgcn_s_setprio(1);
#pragma unroll
    for (int f = 0; f < 4; f++) {              // QK^T
      floatx4 s4 = floatx4{0.f, 0.f, 0.f, 0.f};
      const int row = f * 16 + lr;
#pragma unroll
      for (int kc = 0; kc < 4; kc++) {
        const half8 kfq = *(const half8*)((const char*)Ks + row * 256 +
                            ((kc * 64 + g * 16) ^ ((row & 7) << 4)));
        s4 = __builtin_amdgcn_mfma_f32_16x16x32_f16(qf[kc], kfq, s4, 0, 0, 0);
      }
      sfr[f] = s4;
    }
    __builtin_amdgcn_s_setprio(0);
    if (kt == qt) {                            // diagonal causal mask
#pragma unroll
      for (int f = 0; f < 4; f++) {
        const int key = kt * 64 + f * 16 + lr;
#pragma unroll
        for (int j = 0; j < 4; j++) {
          const int qrow = qt * 64 + w * 16 + g * 4 + j;
          if (key > qrow) sfr[f][j] = -1e30f;
        }
      }
    }
    float al[4];
#pragma unroll
    for (int j = 0; j < 4; j++) {              // online softmax per row
      float pm = fmaxf(fmaxf(sfr[0][j], sfr[1][j]), fmaxf(sfr[2][j], sfr[3][j]));
      pm = fmaxf(pm, __shfl_xor(pm, 1)); pm = fmaxf(pm, __shfl_xor(pm, 2));
      pm = fmaxf(pm, __shfl_xor(pm, 4)); pm = fmaxf(pm, __shfl_xor(pm, 8));
      const float mn = fmaxf(mrun[j], pm);
      al[j] = __expf(mrun[j] - mn);
      mrun[j] = mn;
      float rs = 0.f;
#pragma unroll
      for (int f = 0; f < 4; f++) {
        const float p = __expf(sfr[f][j] - mn);
        sfr[f][j] = p; rs += p;
      }
      rs += __shfl_xor(rs, 1); rs += __shfl_xor(rs, 2);
      rs += __shfl_xor(rs, 4); rs += __shfl_xor(rs, 8);
      lrun[j] = lrun[j] * al[j] + rs;
    }
#pragma unroll
    for (int nf = 0; nf < 8; nf++)
#pragma unroll
      for (int j = 0; j < 4; j++) acc[nf][j] *= al[j];
#pragma unroll
    for (int f = 0; f < 4; f++)                // P -> per-wave LDS (swizzled)
#pragma unroll
      for (int j = 0; j < 4; j++) {
        const int row = g * 4 + j;
        const int byteoff = (row * 128 + (f * 16 + lr) * 2) ^ ((row & 7) << 4);
        *(f16*)((char*)pw + byteoff) = (f16)sfr[f][j];
      }
    __builtin_amdgcn_s_setprio(1);
#pragma unroll
    for (int kc = 0; kc < 2; kc++) {           // PV
      const half8 pf = *(const half8*)((const char*)pw + lr * 128 +
                         ((kc * 64 + g * 16) ^ ((lr & 7) << 4)));
#pragma unroll
      for (int nf = 0; nf < 8; nf++) {
        const int vrow = nf * 16 + lr;
        const half8 vfr = *(const half8*)((const char*)Vs + vrow * 128 +
                            ((kc * 64 + g * 16) ^ ((vrow & 7) << 4)));
        acc[nf] = __builtin_amdgcn_mfma_f32_16x16x32_f16(pf, vfr, acc[nf], 0, 0, 0);
      }
    }
    __builtin_amdgcn_s_setprio(0);
    __syncthreads();
  }
  const long orow = (long)b * kS + q0 + w * 16;
#pragma unroll
  for (int j = 0; j < 4; j++) {
    const float inv = 1.0f / lrun[j];
    const int r = g * 4 + j;
#pragma unroll
    for (int nf = 0; nf < 8; nf++)
      ctx[(orow + r) * kH + h * kHD + nf * 16 + lr] = (f16)(acc[nf][j] * inv);
  }
}

// -- residual 1: h2 = hidden + ls*((P0+P1) * sigmoid(g+bg)); f16 P and g -----
__global__ __launch_bounds__(256) void combine1_kernel(
    const float* __restrict__ hid, const f16* __restrict__ a0,
    const f16* __restrict__ a1, const f16* __restrict__ glin,
    const float* __restrict__ bg, const float* __restrict__ ls,
    float* __restrict__ out)
{
  const long i = (long)blockIdx.x * 256 + threadIdx.x;
  const float4 hv = ((const float4*)hid)[i];
  const half4 av = ((const half4*)a0)[i];
  const half4 aw = ((const half4*)a1)[i];
  const half4 gv = ((const half4*)glin)[i];
  const int c = (int)(i & 511);
  const float4 lv = ((const float4*)ls)[c];
  const float4 bv = ((const float4*)bg)[c];
  float4 o;
  o.x = hv.x + lv.x * ((float)av[0] + (float)aw[0]) / (1.f + __expf(-((float)gv[0] + bv.x)));
  o.y = hv.y + lv.y * ((float)av[1] + (float)aw[1]) / (1.f + __expf(-((float)gv[1] + bv.y)));
  o.z = hv.z + lv.z * ((float)av[2] + (float)aw[2]) / (1.f + __expf(-((float)gv[2] + bv.z)));
  o.w = hv.w + lv.w * ((float)av[3] + (float)aw[3]) / (1.f + __expf(-((float)gv[3] + bv.w)));
  ((float4*)out)[i] = o;
}

// ---------------- router: logits(fp32) -> softmax -> top2 -> gates ----------
__global__ __launch_bounds__(256) void router_kernel(
    const float* __restrict__ x, const float* __restrict__ rw,
    int* __restrict__ eidx, float* __restrict__ gates)
{
  const int t = blockIdx.x * 4 + (threadIdx.x >> 6);
  const int l = threadIdx.x & 63;
  const float* xr = x + (long)t * kH;
  float a[8] = {0.f, 0.f, 0.f, 0.f, 0.f, 0.f, 0.f, 0.f};
  for (int it = 0; it < kH / 64; it++) {
    const float xv = xr[it * 64 + l];
    const float* r = rw + (long)(it * 64 + l) * kE;
#pragma unroll
    for (int e = 0; e < 8; e++) a[e] += xv * r[e];
  }
#pragma unroll
  for (int e = 0; e < 8; e++)
#pragma unroll
    for (int m = 1; m < 64; m <<= 1) a[e] += __shfl_xor(a[e], m);
  if (l == 0) {
    float mx = a[0];
#pragma unroll
    for (int e = 1; e < 8; e++) mx = fmaxf(mx, a[e]);
    float p[8];
#pragma unroll
    for (int e = 0; e < 8; e++) p[e] = __expf(a[e] - mx);
    int i1 = 0; float v1 = p[0];
#pragma unroll
    for (int e = 1; e < 8; e++) if (p[e] > v1) { v1 = p[e]; i1 = e; }
    int i2 = -1; float v2 = -1.f;
#pragma unroll
    for (int e = 0; e < 8; e++) if (e != i1 && p[e] > v2) { v2 = p[e]; i2 = e; }
    const float inv = 1.f / (v1 + v2);
    eidx[t * 2] = i1; eidx[t * 2 + 1] = i2;
    gates[t * 2] = v1 * inv; gates[t * 2 + 1] = v2 * inv;
  }
}

// ---------------- deterministic capacity scan (single wave) -----------------
__global__ void scan_kernel(const int* __restrict__ eidx, int* __restrict__ slot,
                            int* __restrict__ counts)
{
  const int l = threadIdx.x;
  int base[8] = {0, 0, 0, 0, 0, 0, 0, 0};
  const unsigned long long lt = (1ull << l) - 1ull;
  for (int it = 0; it < kTK / 64; it++) {
    const int i = it * 64 + l;
    const int e = eidx[i];
    int mypos = 0;
#pragma unroll
    for (int ex = 0; ex < 8; ex++) {
      const unsigned long long mk = __ballot(e == ex);
      if (e == ex) mypos = base[ex] + __popcll(mk & lt);
      base[ex] += __popcll(mk);
    }
    slot[i] = (mypos < kCAP) ? e * kCAP + mypos : -1;
  }
  if (l == 0) {
#pragma unroll
    for (int ex = 0; ex < 8; ex++) counts[ex] = min(base[ex], kCAP);
  }
}

// ---------------- scatter tokens into expert buffers ------------------------
__global__ __launch_bounds__(256) void scatter_kernel(
    const f16* __restrict__ xh, const int* __restrict__ slot, f16* __restrict__ buf)
{
  const int i = blockIdx.x;
  const int s = slot[i];
  if (s < 0) return;
  const long t = i >> 1;
  ((half8*)(buf + (long)s * kH))[threadIdx.x] =
      ((const half8*)(xh + t * kH))[threadIdx.x];
}

// --- final combine: sum 4 f16 split-K partials + bias + gate + residual -----
__global__ __launch_bounds__(256) void combine2_kernel(
    const float* __restrict__ hid2, const f16* __restrict__ P,
    const int* __restrict__ slot, const float* __restrict__ gates,
    const float* __restrict__ b2, const float* __restrict__ ls,
    float* __restrict__ out, long pS)
{
  const int t = blockIdx.x;
  const int c = threadIdx.x * 8;
  float m[8] = {0.f, 0.f, 0.f, 0.f, 0.f, 0.f, 0.f, 0.f};
#pragma unroll
  for (int ks = 0; ks < 2; ks++) {
    const int s = slot[t * 2 + ks];
    if (s < 0) continue;
    const float gte = gates[t * 2 + ks];
    const int e = s / kCAP;
    const long ro = (long)s * kH + c;
    float acc8[8];
    const float4 ba = *(const float4*)&b2[e * kH + c];
    const float4 bb = *(const float4*)&b2[e * kH + c + 4];
    acc8[0] = ba.x; acc8[1] = ba.y; acc8[2] = ba.z; acc8[3] = ba.w;
    acc8[4] = bb.x; acc8[5] = bb.y; acc8[6] = bb.z; acc8[7] = bb.w;
#pragma unroll
    for (int q = 0; q < 4; q++) {
      const half8 p = *(const half8*)&P[q * pS + ro];
#pragma unroll
      for (int j = 0; j < 8; j++) acc8[j] += (float)p[j];
    }
#pragma unroll
    for (int j = 0; j < 8; j++) m[j] += gte * acc8[j];
  }
  const float* hp = hid2 + (long)t * kH + c;
  float* op = out + (long)t * kH + c;
#pragma unroll
  for (int j = 0; j < 8; j++) op[j] = hp[j] + ls[c + j] * m[j];
}

// ============================================================================
extern "C" void kernel_launch(void* const* d_in, const int* in_sizes, int n_in,
                              void* d_out, int out_size, void* d_ws, size_t ws_size,
                              hipStream_t stream)
{
  (void)in_sizes; (void)n_in;
  const float* hidden   = (const float*)d_in[0];
  const float* ln1s     = (const float*)d_in[2];
  const float* ln1b     = (const float*)d_in[3];
  const float* ln2s     = (const float*)d_in[4];
  const float* ln2b     = (const float*)d_in[5];
  const float* Wq       = (const float*)d_in[6];
  const float* Wk       = (const float*)d_in[7];
  const float* Wv       = (const float*)d_in[8];
  const float* Wo       = (const float*)d_in[9];
  const float* Wg       = (const float*)d_in[10];
  const float* bg       = (const float*)d_in[11];
  const float* ls_attn  = (const float*)d_in[12];
  const float* ls_moe   = (const float*)d_in[13];
  const float* router_w = (const float*)d_in[14];
  const float* W1       = (const float*)d_in[15];
  const float* b1       = (const float*)d_in[16];
  const float* W2       = (const float*)d_in[17];
  const float* b2       = (const float*)d_in[18];

  char* ws = (char*)d_ws;
  size_t off = 0;
  auto take = [&](size_t b) { size_t r = off; off += (b + 255) & ~(size_t)255; return r; };
  const size_t o_wT   = take(5ULL * kH * kH * 2);              // WqT..WgT,WoT f16
  const size_t o_w1t  = take((size_t)kE * kF * kH * 2);        // W1^T f16
  const size_t o_w2t  = take((size_t)kE * kH * kF * 2);        // W2^T f16
  const size_t o_xn   = take((size_t)kT * kH * 2);             // LN1 out f16
  const size_t o_qkvg = take(4ULL * kT * kH * 4);              // qkvg region
  const size_t o_tab  = take(2ULL * kS * 64 * 4);              // rope cos/sin
  const size_t o_qr   = take(3ULL * kT * kH * 2);              // qr, kr, vt f16
  const size_t o_ctx  = take((size_t)kT * kH * 2);             // attn out f16
  const size_t o_h2   = take((size_t)kT * kH * 4);             // residual fp32
  const size_t o_sm   = take(1 << 20);                         // routing small
  const size_t o_hmid = take((size_t)kE * kCAP * kF * 2);      // expert mid f16
  if (off > ws_size) { hipMemsetAsync(d_out, 0xFF, (size_t)out_size * 4, stream); return; }

  f16* wT    = (f16*)(ws + o_wT);
  f16* w1t   = (f16*)(ws + o_w1t);
  f16* w2t   = (f16*)(ws + o_w2t);
  f16* xn    = (f16*)(ws + o_xn);
  float* tabc = (float*)(ws + o_tab);
  float* tabs = tabc + (size_t)kS * 64;
  f16* qr  = (f16*)(ws + o_qr);
  f16* kr  = qr + (size_t)kT * kH;
  f16* vt  = kr + (size_t)kT * kH;
  f16* ctx = (f16*)(ws + o_ctx);
  float* h2 = (float*)(ws + o_h2);
  int* eidx    = (int*)(ws + o_sm);
  float* gates = (float*)(ws + o_sm + 65536);
  int* slot    = (int*)(ws + o_sm + 131072);
  int* counts  = (int*)(ws + o_sm + 196608);
  f16* hmid = (f16*)(ws + o_hmid);

  // qkvg region layout (f16 qkvg outputs + temporal aliases), S2 = kT*kH*2 B
  const size_t S2 = (size_t)kT * kH * 2;
  char* R = ws + o_qkvg;
  f16* qh = (f16*)(R + 0 * S2);          // dead after rope
  f16* kh = (f16*)(R + 1 * S2);          // dead after rope
  f16* vh = (f16*)(R + 2 * S2);          // dead after V-transpose
  f16* gh = (f16*)(R + 3 * S2);          // dead after combine1
  float* x2f = (float*)(R + 4 * S2);     // LN2 fp32 (router input)
  f16* x2h   = (f16*)(R + 6 * S2);       // LN2 f16 (expert input)
  f16* woPh  = (f16*)(R + 0 * S2);       // Wo split-K partials (2x S2), over q/k
  f16* buf  = qr;                        // expert input buffers (qr region dead)
  // MoE GEMM2 split-K=4 f16 partials: w1t region (dead after GEMM1), 4x42MB
  f16* Ph = (f16*)(ws + o_w1t);
  const long pS = (long)kE * kCAP * kH;  // stride between partial buffers

  const long HH = (long)kH * kH;

  // 1. LN1 + batched small weight transposes
  ln_kernel<<<kT, 256, 0, stream>>>(hidden, ln1s, ln1b, xn, nullptr);
  transpose_cvt5<<<dim3(32, 32, 5), 256, 0, stream>>>(Wq, Wk, Wv, Wg, Wo, wT);
  // 2. fused QKV+gate GEMMs, f16 outputs; XCD remap on (B fits L2)
  gemm8p_kernel<4, 1, true><<<dim3(kH / 256, kT / 256, 4), 512, 0, stream>>>(
      xn, wT, qh, nullptr, nullptr, kT, kH, kH, kH, kH,
      0L, HH, (long)kT * kH, 0L, 0L);
  // 3. RoPE (f16 inputs)
  rope_table_kernel<<<(kS * 64 + 255) / 256, 256, 0, stream>>>(tabc, tabs);
  rope_kernel<<<kT, 256, 0, stream>>>(qh, kh, tabc, tabs, qr, kr);
  // 4. V transpose to [BH][HD][S] (f16 -> f16)
  for (int b = 0; b < kB; b++)
    transpose_f16<<<dim3(kHD / 64, kS / 64, kNH), 256, 0, stream>>>(
        vh + (size_t)b * kS * kH, vt + (size_t)b * kNH * kHD * kS,
        kH, kS, 128L, (long)kHD * kS);
  // 5. attention, QBLK=64, single-buffer (4 blocks/CU; grid 1024 % 8 == 0)
  attn_kernel<<<dim3(kS / 64, kNH, kB), 256, 0, stream>>>(qr, kr, vt, ctx);
  // 6. Wo GEMM, split-K=2, f16 partials into the dead q/k slots
  gemm8p_kernel<4, 2, true><<<dim3(kH / 256, kT / 256, 2), 512, 0, stream>>>(
      ctx, wT + 4 * HH, woPh, nullptr, nullptr, kT, kH, 1024, kH, kH,
      0L, 0L, 0L, (long)kT * kH, 0L);
  // 7. gated residual (sums the two Wo f16 partials, f16 gate)
  combine1_kernel<<<(kT * kH / 4) / 256, 256, 0, stream>>>(
      hidden, woPh, woPh + (size_t)kT * kH, gh, bg, ls_attn, h2);
  // 8. LN2 (f16 for experts, fp32 for router)
  ln_kernel<<<kT, 256, 0, stream>>>(h2, ln2s, ln2b, x2h, x2f);
  // 9-11. routing
  router_kernel<<<kT / 4, 256, 0, stream>>>(x2f, router_w, eidx, gates);
  scan_kernel<<<1, 64, 0, stream>>>(eidx, slot, counts);
  scatter_kernel<<<kTK, 256, 0, stream>>>(x2h, slot, buf);
  // 12. W1 transpose here: w1t L3-warm for GEMM1
  transpose_cvt<<<dim3(kF / 64, kH / 64, kE), 256, 0, stream>>>(
      W1, w1t, kF, kH, (long)kH * kF, (long)kF * kH);
  // 13. expert GEMM1 + gelu -- default order, no remap (r5/r8)
  gemm8p_kernel<2, 1, false><<<dim3(kF / 256, kCAP / 256, kE), 512, 0, stream>>>(
      buf, w1t, hmid, b1, counts, kCAP, kF, kH, kH, kH,
      (long)kCAP * kH, (long)kF * kH, (long)kCAP * kF, 0L, (long)kF);
  // 14. W2 transpose here: w2t L3-warm for GEMM2
  transpose_cvt<<<dim3(kH / 64, kF / 64, kE), 256, 0, stream>>>(
      W2, w2t, kH, kF, (long)kF * kH, (long)kH * kF);
  // 15. expert GEMM2, split-K=4, f16 partials
  gemm8p_kernel<4, 4, false><<<dim3(kH / 256, kCAP / 256, 4 * kE), 512, 0, stream>>>(
      hmid, w2t, Ph, nullptr, counts, kCAP, kH, 2048, kF, kF,
      (long)kCAP * kF, (long)kH * kF, (long)kCAP * kH, pS, 0L);
  // 16. final combine (adds 4 partials + b2, gates, residual)
  combine2_kernel<<<kT, 256, 0, stream>>>(
      h2, Ph, slot, gates, b2, ls_moe, (float*)d_out, pS);
}